// Round 1
// baseline (951.238 us; speedup 1.0000x reference)
//
#include <hip/hip_runtime.h>

// Problem constants (match reference).
#define BB 32
#define MM 2048
#define NN 2048
#define ROWS 32      // rows of A per block -> MM/ROWS = 64 chunks per batch
#define CHUNKS (MM / ROWS)
#define THREADS 256  // 4 waves

// Native vector type usable with __builtin_nontemporal_load.
typedef float f32x4 __attribute__((ext_vector_type(4)));

// ws layout (floats), all written-before-read (no zeroing needed):
//   [0, BB*CHUNKS*NN)                : At_lambda partials, [b][chunk][col]
//   P0 = BB*CHUNKS*NN, +2*BB*CHUNKS  : per-block {pr, cm} sums
//   P1 = P0 + 2*BB*CHUNKS, +64*4     : finalize per-block {stat,dual,pr,cm}
#define P0 ((size_t)BB * CHUNKS * NN)
#define P1 (P0 + 2 * BB * CHUNKS)
#define FIN_BLOCKS 64

__device__ __forceinline__ float waveReduceSum(float v) {
#pragma unroll
    for (int off = 32; off > 0; off >>= 1)
        v += __shfl_down(v, off, 64);
    return v;  // valid in lane 0
}

// DPP row_shr add: pure VALU, no DS pipe. After shr 1,2,4,8 the lane with
// (lane&15)==15 holds the sum of its 16-lane group. Invalid source lanes
// contribute old=0 (bound_ctrl=false keeps old).
template <int CTRL>
__device__ __forceinline__ float dppAdd(float v) {
    int s = __builtin_amdgcn_update_dpp(0, __builtin_bit_cast(int, v),
                                        CTRL, 0xF, 0xF, false);
    return v + __builtin_bit_cast(float, s);
}

__device__ __forceinline__ float group16Reduce(float v) {
    v = dppAdd<0x111>(v);  // row_shr:1
    v = dppAdd<0x112>(v);  // row_shr:2
    v = dppAdd<0x114>(v);  // row_shr:4
    v = dppAdd<0x118>(v);  // row_shr:8
    return v;              // valid in lane (t&15)==15
}

// Fused single pass over A: per-row dot with x (-> primal/comp partials) and
// per-column accumulation with lam (-> private At_lambda partial slice).
// Structure: explicit next-row prefetch (counted vmcnt), DPP-only in-loop
// reduction (no ds_bpermute chains), 2048 blocks -> 8 blocks/CU.
__global__ __launch_bounds__(THREADS, 8) void fused_main(
    const float* __restrict__ x_hat, const float* __restrict__ lam_hat,
    const float* __restrict__ A, const float* __restrict__ b_pad,
    float* __restrict__ ws) {
    const int b = blockIdx.y;
    const int chunk = blockIdx.x;
    const int m0 = chunk * ROWS;
    const int t = threadIdx.x;

    __shared__ float lamS[ROWS];
    __shared__ __align__(16) float wp[ROWS * 16];

    if (t < ROWS) lamS[t] = lam_hat[b * MM + m0 + t];
    __syncthreads();

    // Each thread owns columns [4t..4t+3] and [1024+4t..1024+4t+3].
    const f32x4* xv = (const f32x4*)(x_hat + (size_t)b * NN);
    const f32x4 x0 = xv[t];
    const f32x4 x1 = xv[256 + t];

    f32x4 at0 = (f32x4)(0.f);
    f32x4 at1 = (f32x4)(0.f);

    const f32x4* Ab = (const f32x4*)(A + ((size_t)b * MM + (size_t)m0) * NN);

    // Prologue: row 0 in flight.
    f32x4 a0 = __builtin_nontemporal_load(Ab + t);
    f32x4 a1 = __builtin_nontemporal_load(Ab + 256 + t);

    for (int r = 0; r < ROWS; ++r) {
        // Prefetch next row (clamped on last iter -> branch-free body).
        const int rn = (r + 1 < ROWS) ? (r + 1) : r;
        const f32x4* np = Ab + (size_t)rn * (NN / 4);
        f32x4 n0 = __builtin_nontemporal_load(np + t);
        f32x4 n1 = __builtin_nontemporal_load(np + 256 + t);

        const float lm = lamS[r];
        f32x4 d = a0 * x0 + a1 * x1;
        at0 += a0 * lm;
        at1 += a1 * lm;
        float dot = (d.x + d.y) + (d.z + d.w);
        dot = group16Reduce(dot);  // pure VALU
        if ((t & 15) == 15) wp[r * 16 + (t >> 4)] = dot;

        a0 = n0;
        a1 = n1;
    }
    __syncthreads();

    // Wave 0 finalizes: row t sums its 16 group-partials, then block-wide
    // pr/cm reduce across the 32 rows (lanes >= ROWS contribute 0).
    if (t < 64) {
        float pr = 0.f, cm = 0.f;
        if (t < ROWS) {
            const f32x4* wpv = (const f32x4*)wp;
            f32x4 s4 = wpv[t * 4 + 0] + wpv[t * 4 + 1] +
                       wpv[t * 4 + 2] + wpv[t * 4 + 3];
            float y = (s4.x + s4.y) + (s4.z + s4.w) - b_pad[b * MM + m0 + t];
            float lm = lamS[t];
            float ry = fmaxf(y, 0.f);
            pr = ry * ry;
            float c = lm * y;
            cm = c * c;
        }
        pr = waveReduceSum(pr);
        cm = waveReduceSum(cm);
        if (t == 0) {
            float* prcm = ws + P0 + ((size_t)b * CHUNKS + chunk) * 2;
            prcm[0] = pr;
            prcm[1] = cm;
        }
    }

    // Private-slice flush of the At_lambda partial (coalesced, no atomics).
    f32x4* dst = (f32x4*)(ws + ((size_t)b * CHUNKS + chunk) * NN);
    dst[t] = at0;
    dst[256 + t] = at1;
}

// Reduce CHUNKS chunk-partials per column -> stat; plus dual and pr/cm partials.
// Writes per-block {stat,dual,pr,cm} to ws[P1 + blockIdx*4 ..].
__global__ __launch_bounds__(256) void finalize_partial(
    const float* __restrict__ ws_ro, const float* __restrict__ c_pad,
    const float* __restrict__ lam_hat, float* __restrict__ ws) {
    int idx = blockIdx.x * blockDim.x + threadIdx.x;
    int stride = gridDim.x * blockDim.x;
    float stat = 0.f, dual = 0.f, pr = 0.f, cm = 0.f;
    for (int i = idx; i < BB * NN; i += stride) {
        int b = i >> 11;          // / NN
        int col = i & (NN - 1);
        const float* p = ws_ro + (size_t)b * CHUNKS * NN + col;
        float s = 0.f;
#pragma unroll 16
        for (int k = 0; k < CHUNKS; ++k) s += p[(size_t)k * NN];
        float v = s + c_pad[i];
        stat += v * v;
        float l = lam_hat[i];
        float rn = fmaxf(-l, 0.f);
        dual += rn * rn;
    }
    for (int i = idx; i < BB * CHUNKS; i += stride) {
        pr += ws_ro[P0 + 2 * i];
        cm += ws_ro[P0 + 2 * i + 1];
    }
    stat = waveReduceSum(stat);
    dual = waveReduceSum(dual);
    pr = waveReduceSum(pr);
    cm = waveReduceSum(cm);
    __shared__ float s[16];
    int wave = threadIdx.x >> 6, lane = threadIdx.x & 63;
    if (lane == 0) {
        s[wave * 4 + 0] = stat; s[wave * 4 + 1] = dual;
        s[wave * 4 + 2] = pr;   s[wave * 4 + 3] = cm;
    }
    __syncthreads();
    if (threadIdx.x < 4) {
        float v = s[threadIdx.x] + s[4 + threadIdx.x] + s[8 + threadIdx.x] + s[12 + threadIdx.x];
        ws[P1 + (size_t)blockIdx.x * 4 + threadIdx.x] = v;
    }
}

// Reduce FIN_BLOCKS x {stat,dual,pr,cm} and apply loss weights.
__global__ __launch_bounds__(256) void combine_kernel(
    const float* __restrict__ ws_ro, float* __restrict__ out) {
    const int t = threadIdx.x;
    const int wave = t >> 6;   // category: 0=stat 1=dual 2=pr 3=cm
    const int lane = t & 63;
    float v = ws_ro[P1 + (size_t)lane * 4 + wave];  // FIN_BLOCKS == 64
    v = waveReduceSum(v);
    __shared__ float s[4];
    if (lane == 0) s[wave] = v;
    __syncthreads();
    if (t == 0) {
        const float invBM = 1.0f / (float)(BB * MM);
        const float invBN = 1.0f / (float)(BB * NN);
        float stat = s[0] * invBN;
        float dual = s[1] * invBM;
        float primal = s[2] * invBM;
        float comp = s[3] * invBM;
        out[0] = 0.1f * primal + 0.1f * dual + 0.6f * stat + 0.2f * comp;
    }
}

extern "C" void kernel_launch(void* const* d_in, const int* in_sizes, int n_in,
                              void* d_out, int out_size, void* d_ws, size_t ws_size,
                              hipStream_t stream) {
    const float* x_hat   = (const float*)d_in[0];
    const float* lam_hat = (const float*)d_in[1];
    const float* A       = (const float*)d_in[2];
    const float* b_pad   = (const float*)d_in[3];
    const float* c_pad   = (const float*)d_in[4];
    // d_in[5]/d_in[6] (masks) unused by the reference forward.
    float* out = (float*)d_out;
    float* ws = (float*)d_ws;

    dim3 grid(CHUNKS, BB);
    fused_main<<<grid, THREADS, 0, stream>>>(x_hat, lam_hat, A, b_pad, ws);

    finalize_partial<<<FIN_BLOCKS, 256, 0, stream>>>(ws, c_pad, lam_hat, ws);

    combine_kernel<<<1, 256, 0, stream>>>(ws, out);
}

// Round 2
// 853.068 us; speedup vs baseline: 1.1151x; 1.1151x over previous
//
#include <hip/hip_runtime.h>

// Problem constants (match reference).
#define BB 32
#define MM 2048
#define NN 2048
#define ROWS 32      // rows of A per block -> MM/ROWS = 64 chunks per batch
#define CHUNKS (MM / ROWS)
#define THREADS 256  // 4 waves

// Native vector type usable with __builtin_nontemporal_load.
typedef float f32x4 __attribute__((ext_vector_type(4)));

// ws layout (floats), all written-before-read (no zeroing needed):
//   [0, BB*CHUNKS*NN)                : At_lambda partials, [b][chunk][col]
//   P0 = BB*CHUNKS*NN, +2*BB*CHUNKS  : per-block {pr, cm} sums
//   P1 = P0 + 2*BB*CHUNKS, +64*4     : finalize per-block {stat,dual,pr,cm}
#define P0 ((size_t)BB * CHUNKS * NN)
#define P1 (P0 + 2 * BB * CHUNKS)
#define FIN_BLOCKS 64

__device__ __forceinline__ float waveReduceSum(float v) {
#pragma unroll
    for (int off = 32; off > 0; off >>= 1)
        v += __shfl_down(v, off, 64);
    return v;  // valid in lane 0
}

// DPP row_shr add: pure VALU, no DS pipe. After shr 1,2,4,8 the lane with
// (lane&15)==15 holds the sum of its 16-lane group. Invalid source lanes
// contribute old=0 (bound_ctrl=false keeps old).
template <int CTRL>
__device__ __forceinline__ float dppAdd(float v) {
    int s = __builtin_amdgcn_update_dpp(0, __builtin_bit_cast(int, v),
                                        CTRL, 0xF, 0xF, false);
    return v + __builtin_bit_cast(float, s);
}

__device__ __forceinline__ float group16Reduce(float v) {
    v = dppAdd<0x111>(v);  // row_shr:1
    v = dppAdd<0x112>(v);  // row_shr:2
    v = dppAdd<0x114>(v);  // row_shr:4
    v = dppAdd<0x118>(v);  // row_shr:8
    return v;              // valid in lane (t&15)==15
}

// Fused single pass over A: per-row dot with x (-> primal/comp partials) and
// per-column accumulation with lam (-> private At_lambda partial slice).
// Structure: explicit next-row prefetch, DPP-only in-loop reduction.
// __launch_bounds__(256, 4): VGPR cap 128 -- R1's (256,8) cap of 64 forced
// ~36 B/thread/iter of scratch spills (622 MB observed WRITE_SIZE).
__global__ __launch_bounds__(THREADS, 4) void fused_main(
    const float* __restrict__ x_hat, const float* __restrict__ lam_hat,
    const float* __restrict__ A, const float* __restrict__ b_pad,
    float* __restrict__ ws) {
    const int b = blockIdx.y;
    const int chunk = blockIdx.x;
    const int m0 = chunk * ROWS;
    const int t = threadIdx.x;

    __shared__ float lamS[ROWS];
    __shared__ __align__(16) float wp[ROWS * 16];

    if (t < ROWS) lamS[t] = lam_hat[b * MM + m0 + t];
    __syncthreads();

    // Each thread owns columns [4t..4t+3] and [1024+4t..1024+4t+3].
    const f32x4* xv = (const f32x4*)(x_hat + (size_t)b * NN);
    const f32x4 x0 = xv[t];
    const f32x4 x1 = xv[256 + t];

    f32x4 at0 = (f32x4)(0.f);
    f32x4 at1 = (f32x4)(0.f);

    const f32x4* Ab = (const f32x4*)(A + ((size_t)b * MM + (size_t)m0) * NN);

    // Prologue: row 0 in flight.
    f32x4 a0 = __builtin_nontemporal_load(Ab + t);
    f32x4 a1 = __builtin_nontemporal_load(Ab + 256 + t);

#define ROW_BODY(r)                                              \
    do {                                                         \
        const float lm = lamS[r];                                \
        f32x4 d = a0 * x0 + a1 * x1;                             \
        at0 += a0 * lm;                                          \
        at1 += a1 * lm;                                          \
        float dot = (d.x + d.y) + (d.z + d.w);                   \
        dot = group16Reduce(dot);                                \
        if ((t & 15) == 15) wp[(r) * 16 + (t >> 4)] = dot;       \
    } while (0)

    for (int r = 0; r < ROWS - 1; ++r) {
        // Prefetch next row while computing on the current one.
        const f32x4* np = Ab + (size_t)(r + 1) * (NN / 4);
        f32x4 n0 = __builtin_nontemporal_load(np + t);
        f32x4 n1 = __builtin_nontemporal_load(np + 256 + t);

        ROW_BODY(r);

        a0 = n0;
        a1 = n1;
    }
    ROW_BODY(ROWS - 1);  // peeled: no clamped re-load of the last row
#undef ROW_BODY
    __syncthreads();

    // Wave 0 finalizes: row t sums its 16 group-partials, then block-wide
    // pr/cm reduce across the 32 rows (lanes >= ROWS contribute 0).
    if (t < 64) {
        float pr = 0.f, cm = 0.f;
        if (t < ROWS) {
            const f32x4* wpv = (const f32x4*)wp;
            f32x4 s4 = wpv[t * 4 + 0] + wpv[t * 4 + 1] +
                       wpv[t * 4 + 2] + wpv[t * 4 + 3];
            float y = (s4.x + s4.y) + (s4.z + s4.w) - b_pad[b * MM + m0 + t];
            float lm = lamS[t];
            float ry = fmaxf(y, 0.f);
            pr = ry * ry;
            float c = lm * y;
            cm = c * c;
        }
        pr = waveReduceSum(pr);
        cm = waveReduceSum(cm);
        if (t == 0) {
            float* prcm = ws + P0 + ((size_t)b * CHUNKS + chunk) * 2;
            prcm[0] = pr;
            prcm[1] = cm;
        }
    }

    // Private-slice flush of the At_lambda partial (coalesced, no atomics).
    f32x4* dst = (f32x4*)(ws + ((size_t)b * CHUNKS + chunk) * NN);
    dst[t] = at0;
    dst[256 + t] = at1;
}

// Reduce CHUNKS chunk-partials per column -> stat; plus dual and pr/cm partials.
// Writes per-block {stat,dual,pr,cm} to ws[P1 + blockIdx*4 ..].
__global__ __launch_bounds__(256) void finalize_partial(
    const float* __restrict__ ws_ro, const float* __restrict__ c_pad,
    const float* __restrict__ lam_hat, float* __restrict__ ws) {
    int idx = blockIdx.x * blockDim.x + threadIdx.x;
    int stride = gridDim.x * blockDim.x;
    float stat = 0.f, dual = 0.f, pr = 0.f, cm = 0.f;
    for (int i = idx; i < BB * NN; i += stride) {
        int b = i >> 11;          // / NN
        int col = i & (NN - 1);
        const float* p = ws_ro + (size_t)b * CHUNKS * NN + col;
        float s = 0.f;
#pragma unroll 16
        for (int k = 0; k < CHUNKS; ++k) s += p[(size_t)k * NN];
        float v = s + c_pad[i];
        stat += v * v;
        float l = lam_hat[i];
        float rn = fmaxf(-l, 0.f);
        dual += rn * rn;
    }
    for (int i = idx; i < BB * CHUNKS; i += stride) {
        pr += ws_ro[P0 + 2 * i];
        cm += ws_ro[P0 + 2 * i + 1];
    }
    stat = waveReduceSum(stat);
    dual = waveReduceSum(dual);
    pr = waveReduceSum(pr);
    cm = waveReduceSum(cm);
    __shared__ float s[16];
    int wave = threadIdx.x >> 6, lane = threadIdx.x & 63;
    if (lane == 0) {
        s[wave * 4 + 0] = stat; s[wave * 4 + 1] = dual;
        s[wave * 4 + 2] = pr;   s[wave * 4 + 3] = cm;
    }
    __syncthreads();
    if (threadIdx.x < 4) {
        float v = s[threadIdx.x] + s[4 + threadIdx.x] + s[8 + threadIdx.x] + s[12 + threadIdx.x];
        ws[P1 + (size_t)blockIdx.x * 4 + threadIdx.x] = v;
    }
}

// Reduce FIN_BLOCKS x {stat,dual,pr,cm} and apply loss weights.
__global__ __launch_bounds__(256) void combine_kernel(
    const float* __restrict__ ws_ro, float* __restrict__ out) {
    const int t = threadIdx.x;
    const int wave = t >> 6;   // category: 0=stat 1=dual 2=pr 3=cm
    const int lane = t & 63;
    float v = ws_ro[P1 + (size_t)lane * 4 + wave];  // FIN_BLOCKS == 64
    v = waveReduceSum(v);
    __shared__ float s[4];
    if (lane == 0) s[wave] = v;
    __syncthreads();
    if (t == 0) {
        const float invBM = 1.0f / (float)(BB * MM);
        const float invBN = 1.0f / (float)(BB * NN);
        float stat = s[0] * invBN;
        float dual = s[1] * invBM;
        float primal = s[2] * invBM;
        float comp = s[3] * invBM;
        out[0] = 0.1f * primal + 0.1f * dual + 0.6f * stat + 0.2f * comp;
    }
}

extern "C" void kernel_launch(void* const* d_in, const int* in_sizes, int n_in,
                              void* d_out, int out_size, void* d_ws, size_t ws_size,
                              hipStream_t stream) {
    const float* x_hat   = (const float*)d_in[0];
    const float* lam_hat = (const float*)d_in[1];
    const float* A       = (const float*)d_in[2];
    const float* b_pad   = (const float*)d_in[3];
    const float* c_pad   = (const float*)d_in[4];
    // d_in[5]/d_in[6] (masks) unused by the reference forward.
    float* out = (float*)d_out;
    float* ws = (float*)d_ws;

    dim3 grid(CHUNKS, BB);
    fused_main<<<grid, THREADS, 0, stream>>>(x_hat, lam_hat, A, b_pad, ws);

    finalize_partial<<<FIN_BLOCKS, 256, 0, stream>>>(ws, c_pad, lam_hat, ws);

    combine_kernel<<<1, 256, 0, stream>>>(ws, out);
}

// Round 3
// 661.511 us; speedup vs baseline: 1.4380x; 1.2896x over previous
//
#include <hip/hip_runtime.h>

// Problem constants (match reference).
#define BB 32
#define MM 2048
#define NN 2048
#define ROWS 64      // rows of A per block -> MM/ROWS = 32 chunks per batch
#define CHUNKS (MM / ROWS)
#define THREADS 256  // 4 waves

// Native vector type usable with __builtin_nontemporal_load.
typedef float f32x4 __attribute__((ext_vector_type(4)));

// ws layout (floats), all written-before-read (no zeroing needed):
//   [0, BB*CHUNKS*NN)                : At_lambda partials, [b][chunk][col]
//   P0 = BB*CHUNKS*NN, +2*BB*CHUNKS  : per-block {pr, cm} sums
//   P1 = P0 + 2*BB*CHUNKS, +FIN*4    : finalize per-block {stat,dual,pr,cm}
#define P0 ((size_t)BB * CHUNKS * NN)
#define P1 (P0 + 2 * BB * CHUNKS)
#define FIN_BLOCKS 128

__device__ __forceinline__ float waveReduceSum(float v) {
#pragma unroll
    for (int off = 32; off > 0; off >>= 1)
        v += __shfl_down(v, off, 64);
    return v;  // valid in lane 0
}

// DPP row_shr add: pure VALU, no DS pipe. After shr 1,2,4,8 the lane with
// (lane&15)==15 holds the sum of its 16-lane group.
template <int CTRL>
__device__ __forceinline__ float dppAdd(float v) {
    int s = __builtin_amdgcn_update_dpp(0, __builtin_bit_cast(int, v),
                                        CTRL, 0xF, 0xF, false);
    return v + __builtin_bit_cast(float, s);
}

__device__ __forceinline__ float group16Reduce(float v) {
    v = dppAdd<0x111>(v);  // row_shr:1
    v = dppAdd<0x112>(v);  // row_shr:2
    v = dppAdd<0x114>(v);  // row_shr:4
    v = dppAdd<0x118>(v);  // row_shr:8
    return v;              // valid in lane (t&15)==15
}

// Fused single pass over A: per-row dot with x (-> primal/comp partials) and
// per-column accumulation with lam (-> private At_lambda partial slice).
// ROWS=64 (R0 geometry: 1024 blocks, CHUNKS=32 halves the partial-reduction
// tail vs R2) + R2's next-row prefetch + DPP-only in-loop reduce.
// (256,4): VGPR cap 128 -- (256,8)'s cap of 64 spilled 622 MB in R1.
__global__ __launch_bounds__(THREADS, 4) void fused_main(
    const float* __restrict__ x_hat, const float* __restrict__ lam_hat,
    const float* __restrict__ A, const float* __restrict__ b_pad,
    float* __restrict__ ws) {
    const int b = blockIdx.y;
    const int chunk = blockIdx.x;
    const int m0 = chunk * ROWS;
    const int t = threadIdx.x;

    __shared__ float lamS[ROWS];
    __shared__ __align__(16) float wp[ROWS * 16];

    if (t < ROWS) lamS[t] = lam_hat[b * MM + m0 + t];
    __syncthreads();

    // Each thread owns columns [4t..4t+3] and [1024+4t..1024+4t+3].
    const f32x4* xv = (const f32x4*)(x_hat + (size_t)b * NN);
    const f32x4 x0 = xv[t];
    const f32x4 x1 = xv[256 + t];

    f32x4 at0 = (f32x4)(0.f);
    f32x4 at1 = (f32x4)(0.f);

    const f32x4* Ab = (const f32x4*)(A + ((size_t)b * MM + (size_t)m0) * NN);

    // Prologue: row 0 in flight.
    f32x4 a0 = __builtin_nontemporal_load(Ab + t);
    f32x4 a1 = __builtin_nontemporal_load(Ab + 256 + t);

#define ROW_BODY(r)                                              \
    do {                                                         \
        const float lm = lamS[r];                                \
        f32x4 d = a0 * x0 + a1 * x1;                             \
        at0 += a0 * lm;                                          \
        at1 += a1 * lm;                                          \
        float dot = (d.x + d.y) + (d.z + d.w);                   \
        dot = group16Reduce(dot);                                \
        if ((t & 15) == 15) wp[(r) * 16 + (t >> 4)] = dot;       \
    } while (0)

    for (int r = 0; r < ROWS - 1; ++r) {
        // Prefetch next row while computing on the current one.
        const f32x4* np = Ab + (size_t)(r + 1) * (NN / 4);
        f32x4 n0 = __builtin_nontemporal_load(np + t);
        f32x4 n1 = __builtin_nontemporal_load(np + 256 + t);

        ROW_BODY(r);

        a0 = n0;
        a1 = n1;
    }
    ROW_BODY(ROWS - 1);  // peeled: no clamped re-load of the last row
#undef ROW_BODY
    __syncthreads();

    // Wave 0 finalizes: row t sums its 16 group-partials, then wave-wide
    // pr/cm reduce across the 64 rows.
    if (t < 64) {
        const f32x4* wpv = (const f32x4*)wp;
        f32x4 s4 = wpv[t * 4 + 0] + wpv[t * 4 + 1] +
                   wpv[t * 4 + 2] + wpv[t * 4 + 3];
        float y = (s4.x + s4.y) + (s4.z + s4.w) - b_pad[b * MM + m0 + t];
        float lm = lamS[t];
        float ry = fmaxf(y, 0.f);
        float pr = ry * ry;
        float c = lm * y;
        float cm = c * c;
        pr = waveReduceSum(pr);
        cm = waveReduceSum(cm);
        if (t == 0) {
            float* prcm = ws + P0 + ((size_t)b * CHUNKS + chunk) * 2;
            prcm[0] = pr;
            prcm[1] = cm;
        }
    }

    // Private-slice flush of the At_lambda partial (coalesced, no atomics).
    f32x4* dst = (f32x4*)(ws + ((size_t)b * CHUNKS + chunk) * NN);
    dst[t] = at0;
    dst[256 + t] = at1;
}

// Reduce CHUNKS chunk-partials per column -> stat; plus dual and pr/cm partials.
// Writes per-block {stat,dual,pr,cm} to ws[P1 + blockIdx*4 ..].
__global__ __launch_bounds__(256) void finalize_partial(
    const float* __restrict__ ws_ro, const float* __restrict__ c_pad,
    const float* __restrict__ lam_hat, float* __restrict__ ws) {
    int idx = blockIdx.x * blockDim.x + threadIdx.x;
    int stride = gridDim.x * blockDim.x;
    float stat = 0.f, dual = 0.f, pr = 0.f, cm = 0.f;
    for (int i = idx; i < BB * NN; i += stride) {
        int b = i >> 11;          // / NN
        int col = i & (NN - 1);
        const float* p = ws_ro + (size_t)b * CHUNKS * NN + col;
        float s = 0.f;
#pragma unroll
        for (int k = 0; k < CHUNKS; ++k) s += p[(size_t)k * NN];
        float v = s + c_pad[i];
        stat += v * v;
        float l = lam_hat[i];
        float rn = fmaxf(-l, 0.f);
        dual += rn * rn;
    }
    for (int i = idx; i < BB * CHUNKS; i += stride) {
        pr += ws_ro[P0 + 2 * i];
        cm += ws_ro[P0 + 2 * i + 1];
    }
    stat = waveReduceSum(stat);
    dual = waveReduceSum(dual);
    pr = waveReduceSum(pr);
    cm = waveReduceSum(cm);
    __shared__ float s[16];
    int wave = threadIdx.x >> 6, lane = threadIdx.x & 63;
    if (lane == 0) {
        s[wave * 4 + 0] = stat; s[wave * 4 + 1] = dual;
        s[wave * 4 + 2] = pr;   s[wave * 4 + 3] = cm;
    }
    __syncthreads();
    if (threadIdx.x < 4) {
        float v = s[threadIdx.x] + s[4 + threadIdx.x] + s[8 + threadIdx.x] + s[12 + threadIdx.x];
        ws[P1 + (size_t)blockIdx.x * 4 + threadIdx.x] = v;
    }
}

// Reduce FIN_BLOCKS x {stat,dual,pr,cm} and apply loss weights.
__global__ __launch_bounds__(256) void combine_kernel(
    const float* __restrict__ ws_ro, float* __restrict__ out) {
    const int t = threadIdx.x;
    const int wave = t >> 6;   // category: 0=stat 1=dual 2=pr 3=cm
    const int lane = t & 63;
    // FIN_BLOCKS == 128: each lane folds two entries.
    float v = ws_ro[P1 + (size_t)lane * 4 + wave]
            + ws_ro[P1 + (size_t)(64 + lane) * 4 + wave];
    v = waveReduceSum(v);
    __shared__ float s[4];
    if (lane == 0) s[wave] = v;
    __syncthreads();
    if (t == 0) {
        const float invBM = 1.0f / (float)(BB * MM);
        const float invBN = 1.0f / (float)(BB * NN);
        float stat = s[0] * invBN;
        float dual = s[1] * invBM;
        float primal = s[2] * invBM;
        float comp = s[3] * invBM;
        out[0] = 0.1f * primal + 0.1f * dual + 0.6f * stat + 0.2f * comp;
    }
}

extern "C" void kernel_launch(void* const* d_in, const int* in_sizes, int n_in,
                              void* d_out, int out_size, void* d_ws, size_t ws_size,
                              hipStream_t stream) {
    const float* x_hat   = (const float*)d_in[0];
    const float* lam_hat = (const float*)d_in[1];
    const float* A       = (const float*)d_in[2];
    const float* b_pad   = (const float*)d_in[3];
    const float* c_pad   = (const float*)d_in[4];
    // d_in[5]/d_in[6] (masks) unused by the reference forward.
    float* out = (float*)d_out;
    float* ws = (float*)d_ws;

    dim3 grid(CHUNKS, BB);
    fused_main<<<grid, THREADS, 0, stream>>>(x_hat, lam_hat, A, b_pad, ws);

    finalize_partial<<<FIN_BLOCKS, 256, 0, stream>>>(ws, c_pad, lam_hat, ws);

    combine_kernel<<<1, 256, 0, stream>>>(ws, out);
}